// Round 10
// baseline (219.709 us; speedup 1.0000x reference)
//
#include <hip/hip_runtime.h>
#include <hip/hip_fp16.h>

// LinkPredictor: 2-layer GCN encode + edge dot decode.
// N=50000, E=800000, IN_CH=128, HID=64.
// R22: channel-split half-tables for L2 residency. Tail triangulation
//     (R19 half requests=neutral, R20 quarter instructions=neutral, R21
//     deeper batching=~neutral, count-gathers-from-200KB-table=FREE) says
//     the gather passes are MISS-LATENCY bound at fixed per-CU outstanding
//     capacity: 6.4MB tables > 4MB XCD-L2 -> random rows miss to L3
//     (~600-900cy). Fix: split every node table into 32-ch halves (3.2MB
//     < 4MB L2) and run each gather pass per-half in separate dispatches:
//     row = 64B = 1 line-request at (predicted) L2-hit latency.
//       h1A/h1B  <- gemm1 (pointer redirect, blocks already do 32-ch halves)
//       agg1A -> t1A;  agg1B+gemm2 fused -> prescaled h2A/h2B (W2 in LDS,
//                t1A row read sequentially; R17/R21-proven wave-local LDS)
//       agg2A -> zA;  agg2B -> zB   (pure sum, R21 prescale algebra)
//       decodeA -> out (partial);  decodeB -> out += (half-dot each)
//     Build byte-identical to R18/R20/R21 (56-58us, atomic-wall proven).
#define INCH 128
#define HIDC 64
#define CAP  64   // row capacity; P(deg>=64 | Poisson(16)) ~ 1e-20

typedef int            v4i __attribute__((ext_vector_type(4)));
typedef float          v4f __attribute__((ext_vector_type(4)));
typedef unsigned int   v4u __attribute__((ext_vector_type(4)));

__device__ inline float2 u2f(unsigned int u) {
    return __half22float2(__builtin_bit_cast(__half2, u));
}
__device__ inline unsigned int f2u(float a, float b) {
    __half2 h = __float22half2_rn(make_float2(a, b));
    return __builtin_bit_cast(unsigned int, h);
}

// --- fused: gemm blocks compute unscaled h1 halves; edge blocks build CSR --
__global__ __launch_bounds__(128, 2) void build_gemm1_kernel(const int* __restrict__ src,
                                                             const int* __restrict__ dst,
                                                             int* __restrict__ count,
                                                             unsigned short* __restrict__ col,
                                                             const float* __restrict__ x,
                                                             const float* __restrict__ W,
                                                             __half* __restrict__ h1A,
                                                             __half* __restrict__ h1B,
                                                             int E, int N, int GB) {
    int b = (int)blockIdx.x;
    if (b >= GB) {
        int eb = b - GB;
        int g = eb & 7;
        int chunkBase = (eb >> 3) * 2048;         // contiguous 2048-edge chunk
        int t = (int)threadIdx.x;
        if (chunkBase + 2048 <= E) {
            v4i s4[4], d4[4];
            #pragma unroll
            for (int i = 0; i < 4; ++i) {         // 8 loads in flight, cached
                int e0 = chunkBase + (i * 128 + t) * 4;
                d4[i] = *(const v4i*)(dst + e0);
                s4[i] = *(const v4i*)(src + e0);
            }
            #pragma unroll
            for (int i = 0; i < 4; ++i) {
                #pragma unroll
                for (int k = 0; k < 4; ++k) {
                    int d = d4[i][k];
                    if (((d >> 4) & 7) == g) {
                        int r = atomicAdd(&count[d], 1);
                        if (r < CAP) col[(size_t)d * CAP + r] = (unsigned short)s4[i][k];
                    }
                }
            }
        } else {
            #pragma unroll
            for (int i = 0; i < 4; ++i) {
                int e0 = chunkBase + (i * 128 + t) * 4;
                for (int e = e0; e < e0 + 4 && e < E; ++e) {
                    int d = dst[e];
                    if (((d >> 4) & 7) == g) {
                        int r = atomicAdd(&count[d], 1);
                        if (r < CAP) col[(size_t)d * CAP + r] = (unsigned short)src[e];
                    }
                }
            }
        }
    } else {
        // ---- gemm1 (no dinv): proven R8/R11 shape; writes 32-ch half row --
        int node = (b >> 1) * 128 + (int)threadIdx.x;
        int ch0 = (b & 1) * 32;
        if (node >= N) return;
        const float4* xr = (const float4*)(x + (size_t)node * INCH);
        float acc[32];
        #pragma unroll
        for (int c = 0; c < 32; ++c) acc[c] = 0.f;
        for (int kc = 0; kc < INCH / 4; ++kc) {
            float4 xk = xr[kc];
            const float* wr = W + (kc * 4) * HIDC + ch0;
            #pragma unroll
            for (int ch = 0; ch < 32; ++ch) acc[ch] = fmaf(xk.x, wr[ch], acc[ch]);
            #pragma unroll
            for (int ch = 0; ch < 32; ++ch) acc[ch] = fmaf(xk.y, wr[HIDC + ch], acc[ch]);
            #pragma unroll
            for (int ch = 0; ch < 32; ++ch) acc[ch] = fmaf(xk.z, wr[2 * HIDC + ch], acc[ch]);
            #pragma unroll
            for (int ch = 0; ch < 32; ++ch) acc[ch] = fmaf(xk.w, wr[3 * HIDC + ch], acc[ch]);
        }
        v4u hv[4];
        #pragma unroll
        for (int k = 0; k < 4; ++k) {
            #pragma unroll
            for (int e = 0; e < 4; ++e) {
                int c2 = k * 4 + e;
                hv[k][e] = f2u(acc[2 * c2], acc[2 * c2 + 1]);
            }
        }
        __half* ht = (b & 1) ? h1B : h1A;
        v4u* hr = (v4u*)(ht + (size_t)node * 32);
        #pragma unroll
        for (int k = 0; k < 4; ++k) hr[k] = hv[k];
    }
}

// --- agg1 half A: gather h1A (unscaled), dinv[src], +b1A, ReLU -> t1A fp16 --
// 4 lanes/node x 16B (row = 64B = ONE line); 64 nodes/block; 16 in flight.
__global__ __launch_bounds__(256) void agg1_half_kernel(const int* __restrict__ count,
                                                        const unsigned short* __restrict__ col,
                                                        const __half* __restrict__ hhalf,
                                                        const float* __restrict__ bhalf,
                                                        __half* __restrict__ thalf, int N) {
    int t = (int)threadIdx.x;
    int g = t >> 2;
    int q = t & 3;
    int node = (int)blockIdx.x * 64 + g;
    if (node >= N) return;
    int cnt = count[node];
    int deg = cnt < CAP ? cnt : CAP;
    float dn = rsqrtf((float)cnt + 1.0f);
    const v4u* z4 = (const v4u*)hhalf;    // row = 4 v4u (64B)
    v4u sf = z4[(size_t)node * 4 + q];
    float2 acc[4];
    #pragma unroll
    for (int j = 0; j < 4; ++j) {
        float2 f = u2f(sf[j]);
        acc[j] = make_float2(f.x * dn, f.y * dn);
    }
    const unsigned short* row = col + (size_t)node * CAP;
    for (int jb = 0; jb < deg; jb += 16) {
        int s[16]; int cv[16]; v4u a[16];
        #pragma unroll
        for (int u = 0; u < 16; ++u) {
            int idx = jb + u;
            s[u] = row[idx < deg ? idx : jb];
        }
        #pragma unroll
        for (int u = 0; u < 16; ++u)
            a[u] = z4[(size_t)s[u] * 4 + q];           // 16 single-line gathers
        #pragma unroll
        for (int u = 0; u < 16; ++u)
            cv[u] = count[s[u]];
        #pragma unroll
        for (int u = 0; u < 16; ++u) {
            if (jb + u < deg) {
                float w = rsqrtf((float)cv[u] + 1.0f);
                #pragma unroll
                for (int j = 0; j < 4; ++j) {
                    float2 f = u2f(a[u][j]);
                    acc[j].x = fmaf(f.x, w, acc[j].x);
                    acc[j].y = fmaf(f.y, w, acc[j].y);
                }
            }
        }
    }
    int ch0 = q * 8;
    v4f bA = *(const v4f*)(bhalf + ch0);
    v4f bB = *(const v4f*)(bhalf + ch0 + 4);
    v4u hv;
    #pragma unroll
    for (int j = 0; j < 4; ++j) {
        float bx = (j < 2) ? bA[2*j]   : bB[2*j-4];
        float by = (j < 2) ? bA[2*j+1] : bB[2*j-3];
        hv[j] = f2u(fmaxf(fmaf(acc[j].x, dn, bx), 0.f),
                    fmaxf(fmaf(acc[j].y, dn, by), 0.f));
    }
    ((v4u*)thalf)[(size_t)node * 4 + q] = hv;
}

// --- agg1 half B + gemm2: gather h1B -> aggB in regs; full row via LDS
// (own B frag + t1A frag from global); matvec W2; write PRE-SCALED h2A/h2B.
__global__ __launch_bounds__(256) void agg1b_gemm2_kernel(const int* __restrict__ count,
                                                          const unsigned short* __restrict__ col,
                                                          const __half* __restrict__ h1B,
                                                          const __half* __restrict__ t1A,
                                                          const float* __restrict__ b1,
                                                          const float* __restrict__ W2,
                                                          __half* __restrict__ h2A,
                                                          __half* __restrict__ h2B, int N) {
    __shared__ float sW2[HIDC * HIDC];   // 16 KB
    __shared__ float sAgg[64][68];       // 17.4 KB, padded
    int t = (int)threadIdx.x;
    {   // stage W2
        const float4* w4 = (const float4*)W2;
        float4* s4 = (float4*)sW2;
        #pragma unroll
        for (int i = 0; i < 4; ++i) s4[t + 256 * i] = w4[t + 256 * i];
    }
    __syncthreads();

    int g = t >> 2;
    int q = t & 3;
    int node = (int)blockIdx.x * 64 + g;
    if (node >= N) return;
    int cnt = count[node];
    int deg = cnt < CAP ? cnt : CAP;
    float dn = rsqrtf((float)cnt + 1.0f);
    const v4u* z4 = (const v4u*)h1B;
    v4u sf = z4[(size_t)node * 4 + q];
    float2 acc[4];
    #pragma unroll
    for (int j = 0; j < 4; ++j) {
        float2 f = u2f(sf[j]);
        acc[j] = make_float2(f.x * dn, f.y * dn);
    }
    const unsigned short* row = col + (size_t)node * CAP;
    for (int jb = 0; jb < deg; jb += 16) {
        int s[16]; int cv[16]; v4u a[16];
        #pragma unroll
        for (int u = 0; u < 16; ++u) {
            int idx = jb + u;
            s[u] = row[idx < deg ? idx : jb];
        }
        #pragma unroll
        for (int u = 0; u < 16; ++u)
            a[u] = z4[(size_t)s[u] * 4 + q];
        #pragma unroll
        for (int u = 0; u < 16; ++u)
            cv[u] = count[s[u]];
        #pragma unroll
        for (int u = 0; u < 16; ++u) {
            if (jb + u < deg) {
                float w = rsqrtf((float)cv[u] + 1.0f);
                #pragma unroll
                for (int j = 0; j < 4; ++j) {
                    float2 f = u2f(a[u][j]);
                    acc[j].x = fmaf(f.x, w, acc[j].x);
                    acc[j].y = fmaf(f.y, w, acc[j].y);
                }
            }
        }
    }
    // B-half channels 32+q*8 .. +7: +b1, ReLU (fp32)
    int ch0 = q * 8;
    {
        v4f bA = *(const v4f*)(b1 + 32 + ch0);
        v4f bB = *(const v4f*)(b1 + 32 + ch0 + 4);
        v4f pA, pB;
        #pragma unroll
        for (int j = 0; j < 4; ++j) {
            float bx = (j < 2) ? bA[2*j]   : bB[2*j-4];
            float by = (j < 2) ? bA[2*j+1] : bB[2*j-3];
            float px = fmaxf(fmaf(acc[j].x, dn, bx), 0.f);
            float py = fmaxf(fmaf(acc[j].y, dn, by), 0.f);
            if (j < 2) { pA[2*j] = px; pA[2*j+1] = py; }
            else       { pB[2*j-4] = px; pB[2*j-3] = py; }
        }
        *(v4f*)(&sAgg[g][32 + ch0])     = pA;
        *(v4f*)(&sAgg[g][32 + ch0 + 4]) = pB;
    }
    {   // A-half fragment from t1A (sequential 16B/lane, cached)
        v4u ta = ((const v4u*)t1A)[(size_t)node * 4 + q];
        v4f pA, pB;
        #pragma unroll
        for (int j = 0; j < 4; ++j) {
            float2 f = u2f(ta[j]);
            if (j < 2) { pA[2*j] = f.x; pA[2*j+1] = f.y; }
            else       { pB[2*j-4] = f.x; pB[2*j-3] = f.y; }
        }
        *(v4f*)(&sAgg[g][ch0])     = pA;
        *(v4f*)(&sAgg[g][ch0 + 4]) = pB;
    }
    // wave-local ordering (4-lane group within one wave)
    __asm__ volatile("s_waitcnt lgkmcnt(0)" ::: "memory");

    // matvec: lane q -> out channels q*16 .. q*16+15
    int oc0 = q * 16;
    float o[16];
    #pragma unroll
    for (int c = 0; c < 16; ++c) o[c] = 0.f;
    const float* aRow = sAgg[g];
    #pragma unroll
    for (int kk = 0; kk < 16; ++kk) {
        v4f a4 = *(const v4f*)(aRow + kk * 4);
        #pragma unroll
        for (int kv = 0; kv < 4; ++kv) {
            float av = a4[kv];
            const float* wr = sW2 + (kk * 4 + kv) * HIDC + oc0;
            v4f w0 = *(const v4f*)(wr);
            v4f w1 = *(const v4f*)(wr + 4);
            v4f w2 = *(const v4f*)(wr + 8);
            v4f w3 = *(const v4f*)(wr + 12);
            #pragma unroll
            for (int c = 0; c < 4; ++c) o[c]      = fmaf(av, w0[c], o[c]);
            #pragma unroll
            for (int c = 0; c < 4; ++c) o[c + 4]  = fmaf(av, w1[c], o[c + 4]);
            #pragma unroll
            for (int c = 0; c < 4; ++c) o[c + 8]  = fmaf(av, w2[c], o[c + 8]);
            #pragma unroll
            for (int c = 0; c < 4; ++c) o[c + 12] = fmaf(av, w3[c], o[c + 12]);
        }
    }
    // write 16 prescaled fp16 channels to the right half table
    v4u hv0, hv1;
    #pragma unroll
    for (int j = 0; j < 4; ++j) hv0[j] = f2u(o[2*j] * dn,     o[2*j+1] * dn);
    #pragma unroll
    for (int j = 0; j < 4; ++j) hv1[j] = f2u(o[8+2*j] * dn,   o[8+2*j+1] * dn);
    __half* hb = (q < 2) ? h2A : h2B;
    v4u* hr = (v4u*)(hb + (size_t)node * 32) + (q & 1) * 2;
    hr[0] = hv0;
    hr[1] = hv1;
}

// --- agg2 half: gather PRE-SCALED h2 half; pure sum; z = dn*sum + b2half ---
__global__ __launch_bounds__(256) void agg2_half_kernel(const int* __restrict__ count,
                                                        const unsigned short* __restrict__ col,
                                                        const __half* __restrict__ hhalf,
                                                        const float* __restrict__ bhalf,
                                                        __half* __restrict__ zhalf, int N) {
    int t = (int)threadIdx.x;
    int g = t >> 2;
    int q = t & 3;
    int node = (int)blockIdx.x * 64 + g;
    if (node >= N) return;
    int cnt = count[node];
    int deg = cnt < CAP ? cnt : CAP;
    float dn = rsqrtf((float)cnt + 1.0f);
    const v4u* z4 = (const v4u*)hhalf;
    v4u sf = z4[(size_t)node * 4 + q];    // self, already dn-scaled
    float2 acc[4];
    #pragma unroll
    for (int j = 0; j < 4; ++j) acc[j] = u2f(sf[j]);
    const unsigned short* row = col + (size_t)node * CAP;
    for (int jb = 0; jb < deg; jb += 16) {
        int s[16]; v4u a[16];
        #pragma unroll
        for (int u = 0; u < 16; ++u) {
            int idx = jb + u;
            s[u] = row[idx < deg ? idx : jb];
        }
        #pragma unroll
        for (int u = 0; u < 16; ++u)
            a[u] = z4[(size_t)s[u] * 4 + q];
        #pragma unroll
        for (int u = 0; u < 16; ++u) {
            if (jb + u < deg) {
                #pragma unroll
                for (int j = 0; j < 4; ++j) {
                    float2 f = u2f(a[u][j]);
                    acc[j].x += f.x;
                    acc[j].y += f.y;
                }
            }
        }
    }
    int ch0 = q * 8;
    v4f bA = *(const v4f*)(bhalf + ch0);
    v4f bB = *(const v4f*)(bhalf + ch0 + 4);
    v4u hv;
    #pragma unroll
    for (int j = 0; j < 4; ++j) {
        float bx = (j < 2) ? bA[2*j]   : bB[2*j-4];
        float by = (j < 2) ? bA[2*j+1] : bB[2*j-3];
        hv[j] = f2u(fmaf(acc[j].x, dn, bx), fmaf(acc[j].y, dn, by));
    }
    ((v4u*)zhalf)[(size_t)node * 4 + q] = hv;
}

// --- decode half: 4 lanes/edge, 8 edges/group; partial (ADD=0) or += (ADD=1)
template<int ADD>
__global__ __launch_bounds__(256) void decode_half_kernel(const int* __restrict__ src,
                                                          const int* __restrict__ dst,
                                                          const __half* __restrict__ zhalf,
                                                          float* __restrict__ out, int E) {
    long long tid = (long long)blockIdx.x * 256 + threadIdx.x;
    int g = (int)(tid >> 2);
    int q = threadIdx.x & 3;
    int e0 = g * 8;
    if (e0 >= E) return;
    const v4u* z4 = (const v4u*)zhalf;    // row = 4 v4u (64B)
    bool full = (e0 + 7 < E);
    int s[8], d[8];
    if (full) {
        v4i sv0 = *(const v4i*)(src + e0);
        v4i sv1 = *(const v4i*)(src + e0 + 4);
        v4i dv0 = *(const v4i*)(dst + e0);
        v4i dv1 = *(const v4i*)(dst + e0 + 4);
        s[0]=sv0.x; s[1]=sv0.y; s[2]=sv0.z; s[3]=sv0.w;
        s[4]=sv1.x; s[5]=sv1.y; s[6]=sv1.z; s[7]=sv1.w;
        d[0]=dv0.x; d[1]=dv0.y; d[2]=dv0.z; d[3]=dv0.w;
        d[4]=dv1.x; d[5]=dv1.y; d[6]=dv1.z; d[7]=dv1.w;
    } else {
        #pragma unroll
        for (int k = 0; k < 8; ++k) {
            int e = e0 + k < E ? e0 + k : e0;
            s[k] = src[e]; d[k] = dst[e];
        }
    }
    v4u a[8], b[8];
    #pragma unroll
    for (int k = 0; k < 8; ++k) a[k] = z4[(size_t)s[k] * 4 + q];
    #pragma unroll
    for (int k = 0; k < 8; ++k) b[k] = z4[(size_t)d[k] * 4 + q];
    float p[8];
    #pragma unroll
    for (int k = 0; k < 8; ++k) {
        float acc = 0.f;
        #pragma unroll
        for (int j = 0; j < 4; ++j) {
            float2 fa = u2f(a[k][j]);
            float2 fb = u2f(b[k][j]);
            acc = fmaf(fa.x, fb.x, acc);
            acc = fmaf(fa.y, fb.y, acc);
        }
        p[k] = acc;
    }
    #pragma unroll
    for (int m = 2; m; m >>= 1) {         // reduce within 4-lane group
        #pragma unroll
        for (int k = 0; k < 8; ++k) p[k] += __shfl_xor(p[k], m, 64);
    }
    if (q == 0) {
        if (full) {
            v4f r0, r1;
            if (ADD) {
                r0 = *(const v4f*)(out + e0);
                r1 = *(const v4f*)(out + e0 + 4);
                #pragma unroll
                for (int k = 0; k < 4; ++k) { r0[k] += p[k]; r1[k] += p[k+4]; }
            } else {
                #pragma unroll
                for (int k = 0; k < 4; ++k) { r0[k] = p[k]; r1[k] = p[k+4]; }
            }
            *(v4f*)(out + e0)     = r0;
            *(v4f*)(out + e0 + 4) = r1;
        } else {
            for (int k = 0; k < 8 && e0 + k < E; ++k) {
                if (ADD) out[e0 + k] += p[k];
                else     out[e0 + k]  = p[k];
            }
        }
    }
}

extern "C" void kernel_launch(void* const* d_in, const int* in_sizes, int n_in,
                              void* d_out, int out_size, void* d_ws, size_t ws_size,
                              hipStream_t stream) {
    const float* x  = (const float*)d_in[0];
    const int*   ei = (const int*)d_in[1];
    const float* W1 = (const float*)d_in[2];
    const float* b1 = (const float*)d_in[3];
    const float* W2 = (const float*)d_in[4];
    const float* b2 = (const float*)d_in[5];
    float* out = (float*)d_out;

    const int hid  = in_sizes[3];            // 64
    const int inch = in_sizes[2] / hid;      // 128
    const int N    = in_sizes[0] / inch;     // 50000
    const int E    = in_sizes[1] / 2;        // 800000
    const int* srcp = ei;
    const int* dstp = ei + E;

    char* p = (char*)d_ws;
    auto alloc = [&](size_t bytes) { char* r = p; p += (bytes + 255) & ~(size_t)255; return r; };
    int*            count = (int*)alloc((size_t)N * 4);
    unsigned short* col   = (unsigned short*)alloc((size_t)N * CAP * 2);  // 6.4 MB
    __half*         h1A   = (__half*)alloc((size_t)N * 32 * 2);           // 3.2 MB halves
    __half*         h1B   = (__half*)alloc((size_t)N * 32 * 2);
    __half*         t1A   = (__half*)alloc((size_t)N * 32 * 2);
    __half*         h2A   = (__half*)alloc((size_t)N * 32 * 2);
    __half*         h2B   = (__half*)alloc((size_t)N * 32 * 2);
    __half*         zA    = (__half*)alloc((size_t)N * 32 * 2);
    __half*         zB    = (__half*)alloc((size_t)N * 32 * 2);

    (void)hipMemsetAsync(count, 0, (size_t)N * 4, stream);

    int GB  = 2 * ((N + 127) / 128);                   // gemm1 blocks (first)
    int EBK = 8 * ((E + 2047) / 2048);                 // 8 partitions x chunks
    build_gemm1_kernel<<<GB + EBK, 128, 0, stream>>>(srcp, dstp, count, col,
                                                     x, W1, h1A, h1B, E, N, GB);

    int AB = (N + 63) / 64;                            // 782 blocks, 64 nodes each
    agg1_half_kernel<<<AB, 256, 0, stream>>>(count, col, h1A, b1, t1A, N);
    agg1b_gemm2_kernel<<<AB, 256, 0, stream>>>(count, col, h1B, t1A, b1, W2,
                                               h2A, h2B, N);
    agg2_half_kernel<<<AB, 256, 0, stream>>>(count, col, h2A, b2,      zA, N);
    agg2_half_kernel<<<AB, 256, 0, stream>>>(count, col, h2B, b2 + 32, zB, N);

    long long groups = ((long long)E + 7) / 8;
    long long blocksD = (groups * 4 + 255) / 256;
    decode_half_kernel<0><<<(int)blocksD, 256, 0, stream>>>(srcp, dstp, zA, out, E);
    decode_half_kernel<1><<<(int)blocksD, 256, 0, stream>>>(srcp, dstp, zB, out, E);
}

// Round 11
// 191.105 us; speedup vs baseline: 1.1497x; 1.1497x over previous
//
#include <hip/hip_runtime.h>
#include <hip/hip_fp16.h>

// LinkPredictor: 2-layer GCN encode + edge dot decode.
// N=50000, E=800000, IN_CH=128, HID=64.
// R23: revert to R21 (186.5us best; R22's half-table split regressed to
//     219.7 -> L2-residency theory falsified). Tail gather passes are now
//     triangulated as random-line SERVICE-RATE bound (~40 G-lines/s):
//     R19 (1/2 requests), R20 (1/4 instructions), R21 (2x depth), R22
//     (1/2 table size) all ~neutral. Build pinned at returning-atomic wall
//     (R13/14/15/16/18). One low-risk lever on top of R21: agg1_gemm2
//     stages W2 as fp16 in LDS (24.6KB -> 16.9KB total) -> block/CU limit
//     moves 6 (LDS) -> 8 (threads), +33% resident waves on the largest
//     tail kernel; W2 reads stay conflict-free/broadcast per-q.
#define INCH 128
#define HIDC 64
#define CAP  64   // row capacity; P(deg>=64 | Poisson(16)) ~ 1e-20

typedef int            v4i __attribute__((ext_vector_type(4)));
typedef float          v4f __attribute__((ext_vector_type(4)));
typedef unsigned int   v4u __attribute__((ext_vector_type(4)));

__device__ inline float2 u2f(unsigned int u) {
    return __half22float2(__builtin_bit_cast(__half2, u));
}
__device__ inline unsigned int f2u(float a, float b) {
    __half2 h = __float22half2_rn(make_float2(a, b));
    return __builtin_bit_cast(unsigned int, h);
}

// --- fused: gemm blocks compute unscaled h1; edge blocks build count+col ---
// (exact R18/R20/R21 kernel: 56-58us measured)
__global__ __launch_bounds__(128, 2) void build_gemm1_kernel(const int* __restrict__ src,
                                                             const int* __restrict__ dst,
                                                             int* __restrict__ count,
                                                             unsigned short* __restrict__ col,
                                                             const float* __restrict__ x,
                                                             const float* __restrict__ W,
                                                             __half* __restrict__ hs,
                                                             int E, int N, int GB) {
    int b = (int)blockIdx.x;
    if (b >= GB) {
        int eb = b - GB;
        int g = eb & 7;
        int chunkBase = (eb >> 3) * 2048;         // contiguous 2048-edge chunk
        int t = (int)threadIdx.x;
        if (chunkBase + 2048 <= E) {
            v4i s4[4], d4[4];
            #pragma unroll
            for (int i = 0; i < 4; ++i) {         // 8 loads in flight, cached
                int e0 = chunkBase + (i * 128 + t) * 4;
                d4[i] = *(const v4i*)(dst + e0);
                s4[i] = *(const v4i*)(src + e0);
            }
            #pragma unroll
            for (int i = 0; i < 4; ++i) {
                #pragma unroll
                for (int k = 0; k < 4; ++k) {
                    int d = d4[i][k];
                    if (((d >> 4) & 7) == g) {
                        int r = atomicAdd(&count[d], 1);
                        if (r < CAP) col[(size_t)d * CAP + r] = (unsigned short)s4[i][k];
                    }
                }
            }
        } else {
            #pragma unroll
            for (int i = 0; i < 4; ++i) {
                int e0 = chunkBase + (i * 128 + t) * 4;
                for (int e = e0; e < e0 + 4 && e < E; ++e) {
                    int d = dst[e];
                    if (((d >> 4) & 7) == g) {
                        int r = atomicAdd(&count[d], 1);
                        if (r < CAP) col[(size_t)d * CAP + r] = (unsigned short)src[e];
                    }
                }
            }
        }
    } else {
        // ---- gemm1 (no dinv): proven R8/R11 shape ----
        int node = (b >> 1) * 128 + (int)threadIdx.x;
        int ch0 = (b & 1) * 32;
        if (node >= N) return;
        const float4* xr = (const float4*)(x + (size_t)node * INCH);
        float acc[32];
        #pragma unroll
        for (int c = 0; c < 32; ++c) acc[c] = 0.f;
        for (int kc = 0; kc < INCH / 4; ++kc) {
            float4 xk = xr[kc];
            const float* wr = W + (kc * 4) * HIDC + ch0;
            #pragma unroll
            for (int ch = 0; ch < 32; ++ch) acc[ch] = fmaf(xk.x, wr[ch], acc[ch]);
            #pragma unroll
            for (int ch = 0; ch < 32; ++ch) acc[ch] = fmaf(xk.y, wr[HIDC + ch], acc[ch]);
            #pragma unroll
            for (int ch = 0; ch < 32; ++ch) acc[ch] = fmaf(xk.z, wr[2 * HIDC + ch], acc[ch]);
            #pragma unroll
            for (int ch = 0; ch < 32; ++ch) acc[ch] = fmaf(xk.w, wr[3 * HIDC + ch], acc[ch]);
        }
        v4u hv[4];
        #pragma unroll
        for (int k = 0; k < 4; ++k) {
            #pragma unroll
            for (int e = 0; e < 4; ++e) {
                int c2 = k * 4 + e;
                hv[k][e] = f2u(acc[2 * c2], acc[2 * c2 + 1]);
            }
        }
        v4u* hr = (v4u*)(hs + (size_t)node * HIDC + ch0);
        #pragma unroll
        for (int k = 0; k < 4; ++k) hr[k] = hv[k];
    }
}

// --- fused aggregate1 + b1 + ReLU + gemm2 -> h2s (fp16, PRE-SCALED) ------
// 8 lanes/node x 16B, 32 nodes/block; 16 rows in flight; W2 fp16 in LDS.
__global__ __launch_bounds__(256) void agg1_gemm2_kernel(const int* __restrict__ count,
                                                         const unsigned short* __restrict__ col,
                                                         const __half* __restrict__ hs,
                                                         const float* __restrict__ b1,
                                                         const float* __restrict__ W2,
                                                         __half* __restrict__ out, int N) {
    __shared__ unsigned int sW2[HIDC * HIDC / 2];  // 8 KB, fp16x2 [k][c/2]
    __shared__ float sAgg[32][68];                 // 8.5 KB, padded vs 256B stride
    int t = (int)threadIdx.x;
    {   // stage W2 as fp16: thread t converts floats [t*16, t*16+16)
        const float4* w4 = (const float4*)(W2 + t * 16);
        unsigned int* sd = sW2 + t * 8;
        #pragma unroll
        for (int i = 0; i < 4; ++i) {
            float4 f = w4[i];
            sd[2 * i]     = f2u(f.x, f.y);
            sd[2 * i + 1] = f2u(f.z, f.w);
        }
    }
    __syncthreads();

    int g = t >> 3;                       // node slot 0..31
    int q = t & 7;                        // 16B fragment of row
    int node = (int)blockIdx.x * 32 + g;
    if (node >= N) return;
    int cnt = count[node];
    int deg = cnt < CAP ? cnt : CAP;
    float dn = rsqrtf((float)cnt + 1.0f);
    const v4u* z8 = (const v4u*)hs;       // 8 fp16 per v4u; row = 8 v4u
    v4u sf = z8[(size_t)node * 8 + q];    // self (unscaled)
    float2 acc[4];
    #pragma unroll
    for (int j = 0; j < 4; ++j) {
        float2 f = u2f(sf[j]);
        acc[j] = make_float2(f.x * dn, f.y * dn);
    }
    const unsigned short* row = col + (size_t)node * CAP;
    for (int jb = 0; jb < deg; jb += 16) {
        int s[16]; int cv[16]; v4u a[16];
        #pragma unroll
        for (int u = 0; u < 16; ++u) {
            int idx = jb + u;
            s[u] = row[idx < deg ? idx : jb];          // clamp -> dup (L1 hit)
        }
        #pragma unroll
        for (int u = 0; u < 16; ++u)
            a[u] = z8[(size_t)s[u] * 8 + q];           // 16 rows in flight
        #pragma unroll
        for (int u = 0; u < 16; ++u)
            cv[u] = count[s[u]];
        #pragma unroll
        for (int u = 0; u < 16; ++u) {
            if (jb + u < deg) {
                float w = rsqrtf((float)cv[u] + 1.0f); // dinv[src]
                #pragma unroll
                for (int j = 0; j < 4; ++j) {
                    float2 f = u2f(a[u][j]);
                    acc[j].x = fmaf(f.x, w, acc[j].x);
                    acc[j].y = fmaf(f.y, w, acc[j].y);
                }
            }
        }
    }
    // +b1, ReLU (fp32), stage row fragment to LDS
    int ch0 = q * 8;
    v4f bA = *(const v4f*)(b1 + ch0);
    v4f bB = *(const v4f*)(b1 + ch0 + 4);
    v4f pA, pB;
    #pragma unroll
    for (int j = 0; j < 4; ++j) {
        float px = fmaxf(fmaf(acc[j].x, dn, (j < 2 ? bA[2*j]   : bB[2*j-4])),   0.f);
        float py = fmaxf(fmaf(acc[j].y, dn, (j < 2 ? bA[2*j+1] : bB[2*j-3])),  0.f);
        if (j < 2) { pA[2*j] = px; pA[2*j+1] = py; }
        else       { pB[2*j-4] = px; pB[2*j-3] = py; }
    }
    *(v4f*)(&sAgg[g][ch0])     = pA;
    *(v4f*)(&sAgg[g][ch0 + 4]) = pB;
    // wave-local ordering: same wave's ds_writes complete before ds_reads
    __asm__ volatile("s_waitcnt lgkmcnt(0)" ::: "memory");

    // matvec: lane computes out channels ch0..ch0+7 from fp16 W2 rows
    float o[8];
    #pragma unroll
    for (int c = 0; c < 8; ++c) o[c] = 0.f;
    const float* aRow = sAgg[g];
    #pragma unroll
    for (int kk = 0; kk < 16; ++kk) {
        v4f a4 = *(const v4f*)(aRow + kk * 4);
        #pragma unroll
        for (int kv = 0; kv < 4; ++kv) {
            float av = a4[kv];
            // 8 halves of W2[k][ch0..ch0+7]: one 16B LDS read
            v4u wv = *(const v4u*)(sW2 + ((kk * 4 + kv) * HIDC + ch0) / 2);
            #pragma unroll
            for (int j = 0; j < 4; ++j) {
                float2 wf = u2f(wv[j]);
                o[2*j]   = fmaf(av, wf.x, o[2*j]);
                o[2*j+1] = fmaf(av, wf.y, o[2*j+1]);
            }
        }
    }
    v4u hv;
    #pragma unroll
    for (int j = 0; j < 4; ++j) hv[j] = f2u(o[2*j] * dn, o[2*j+1] * dn);
    ((v4u*)out)[(size_t)node * 8 + q] = hv;   // PRE-SCALED h2 (dn baked in)
}

// --- aggregate2: gathers PRE-SCALED h2s; plain sum, no per-neighbor scale --
// z[n] = dn * (sum_s h2s_scaled[s] + h2s_scaled[n]) + b2
__global__ __launch_bounds__(256) void aggregate_kernel(const int* __restrict__ count,
                                                        const unsigned short* __restrict__ col,
                                                        const __half* __restrict__ hs,
                                                        const float* __restrict__ bias,
                                                        __half* __restrict__ agg, int N) {
    int t = (int)threadIdx.x;
    int g = t >> 3;
    int q = t & 7;
    int node = (int)blockIdx.x * 32 + g;
    if (node >= N) return;
    int cnt = count[node];
    int deg = cnt < CAP ? cnt : CAP;
    float dn = rsqrtf((float)cnt + 1.0f);
    const v4u* z8 = (const v4u*)hs;
    v4u sf = z8[(size_t)node * 8 + q];    // self, already dn-scaled
    float2 acc[4];
    #pragma unroll
    for (int j = 0; j < 4; ++j) acc[j] = u2f(sf[j]);
    const unsigned short* row = col + (size_t)node * CAP;
    for (int jb = 0; jb < deg; jb += 16) {
        int s[16]; v4u a[16];
        #pragma unroll
        for (int u = 0; u < 16; ++u) {
            int idx = jb + u;
            s[u] = row[idx < deg ? idx : jb];
        }
        #pragma unroll
        for (int u = 0; u < 16; ++u)
            a[u] = z8[(size_t)s[u] * 8 + q];           // 16 rows in flight
        #pragma unroll
        for (int u = 0; u < 16; ++u) {
            if (jb + u < deg) {
                #pragma unroll
                for (int j = 0; j < 4; ++j) {
                    float2 f = u2f(a[u][j]);
                    acc[j].x += f.x;
                    acc[j].y += f.y;
                }
            }
        }
    }
    int ch0 = q * 8;
    v4f bA = *(const v4f*)(bias + ch0);
    v4f bB = *(const v4f*)(bias + ch0 + 4);
    v4u hv;
    #pragma unroll
    for (int j = 0; j < 4; ++j) {
        float bx = (j < 2) ? bA[2*j]   : bB[2*j-4];
        float by = (j < 2) ? bA[2*j+1] : bB[2*j-3];
        hv[j] = f2u(fmaf(acc[j].x, dn, bx), fmaf(acc[j].y, dn, by));
    }
    ((v4u*)agg)[(size_t)node * 8 + q] = hv;
}

// --- decode: 8 lanes per edge, 8 edges per group (R18/R20/R21, proven) ----
__global__ __launch_bounds__(256) void decode_kernel(const int* __restrict__ src,
                                                     const int* __restrict__ dst,
                                                     const __half* __restrict__ z,
                                                     float* __restrict__ out, int E) {
    long long tid = (long long)blockIdx.x * 256 + threadIdx.x;
    int g = (int)(tid >> 3);
    int q = threadIdx.x & 7;
    int e0 = g * 8;
    if (e0 >= E) return;
    const v4u* z8 = (const v4u*)z;                    // 8 fp16 per v4u; row = 8 v4u
    bool full = (e0 + 7 < E);
    int s[8], d[8];
    if (full) {
        v4i sv0 = __builtin_nontemporal_load((const v4i*)(src + e0));
        v4i sv1 = __builtin_nontemporal_load((const v4i*)(src + e0 + 4));
        v4i dv0 = __builtin_nontemporal_load((const v4i*)(dst + e0));
        v4i dv1 = __builtin_nontemporal_load((const v4i*)(dst + e0 + 4));
        s[0]=sv0.x; s[1]=sv0.y; s[2]=sv0.z; s[3]=sv0.w;
        s[4]=sv1.x; s[5]=sv1.y; s[6]=sv1.z; s[7]=sv1.w;
        d[0]=dv0.x; d[1]=dv0.y; d[2]=dv0.z; d[3]=dv0.w;
        d[4]=dv1.x; d[5]=dv1.y; d[6]=dv1.z; d[7]=dv1.w;
    } else {
        #pragma unroll
        for (int k = 0; k < 8; ++k) {
            int e = e0 + k < E ? e0 + k : e0;
            s[k] = src[e]; d[k] = dst[e];
        }
    }
    v4u a[8], b[8];
    #pragma unroll
    for (int k = 0; k < 8; ++k) a[k] = z8[(size_t)s[k] * 8 + q];
    #pragma unroll
    for (int k = 0; k < 8; ++k) b[k] = z8[(size_t)d[k] * 8 + q];
    float p[8];
    #pragma unroll
    for (int k = 0; k < 8; ++k) {
        float acc = 0.f;
        #pragma unroll
        for (int j = 0; j < 4; ++j) {
            float2 fa = u2f(a[k][j]);
            float2 fb = u2f(b[k][j]);
            acc = fmaf(fa.x, fb.x, acc);
            acc = fmaf(fa.y, fb.y, acc);
        }
        p[k] = acc;
    }
    #pragma unroll
    for (int m = 4; m; m >>= 1) {
        #pragma unroll
        for (int k = 0; k < 8; ++k) p[k] += __shfl_xor(p[k], m, 64);
    }
    if (q == 0) {
        if (full) {
            v4f r0; r0.x = p[0]; r0.y = p[1]; r0.z = p[2]; r0.w = p[3];
            v4f r1; r1.x = p[4]; r1.y = p[5]; r1.z = p[6]; r1.w = p[7];
            __builtin_nontemporal_store(r0, (v4f*)(out + e0));
            __builtin_nontemporal_store(r1, (v4f*)(out + e0 + 4));
        } else {
            for (int k = 0; k < 8 && e0 + k < E; ++k) out[e0 + k] = p[k];
        }
    }
}

extern "C" void kernel_launch(void* const* d_in, const int* in_sizes, int n_in,
                              void* d_out, int out_size, void* d_ws, size_t ws_size,
                              hipStream_t stream) {
    const float* x  = (const float*)d_in[0];
    const int*   ei = (const int*)d_in[1];
    const float* W1 = (const float*)d_in[2];
    const float* b1 = (const float*)d_in[3];
    const float* W2 = (const float*)d_in[4];
    const float* b2 = (const float*)d_in[5];
    float* out = (float*)d_out;

    const int hid  = in_sizes[3];            // 64
    const int inch = in_sizes[2] / hid;      // 128
    const int N    = in_sizes[0] / inch;     // 50000
    const int E    = in_sizes[1] / 2;        // 800000
    const int* srcp = ei;
    const int* dstp = ei + E;

    char* p = (char*)d_ws;
    auto alloc = [&](size_t bytes) { char* r = p; p += (bytes + 255) & ~(size_t)255; return r; };
    int*            count = (int*)alloc((size_t)N * 4);
    unsigned short* col   = (unsigned short*)alloc((size_t)N * CAP * 2);  // 6.4 MB
    __half*         h1s   = (__half*)alloc((size_t)N * HIDC * 2);         // fp16 tables
    __half*         h2s   = (__half*)alloc((size_t)N * HIDC * 2);
    __half*         zt    = (__half*)alloc((size_t)N * HIDC * 2);

    (void)hipMemsetAsync(count, 0, (size_t)N * 4, stream);

    int GB  = 2 * ((N + 127) / 128);                   // gemm1 blocks (first)
    int EBK = 8 * ((E + 2047) / 2048);                 // 8 partitions x chunks
    build_gemm1_kernel<<<GB + EBK, 128, 0, stream>>>(srcp, dstp, count, col,
                                                     x, W1, h1s, E, N, GB);

    // fused aggregate1 + ReLU + gemm2 -> h2s (pre-scaled), 32 nodes/block
    agg1_gemm2_kernel<<<(N + 31) / 32, 256, 0, stream>>>(count, col, h1s, b1, W2, h2s, N);

    aggregate_kernel<<<(N + 31) / 32, 256, 0, stream>>>(count, col, h2s, b2, zt, N);

    long long groups = ((long long)E + 7) / 8;
    long long blocksD = (groups * 8 + 255) / 256;
    decode_kernel<<<(int)blocksD, 256, 0, stream>>>(srcp, dstp, zt, out, E);
}